// Round 1
// baseline (375.033 us; speedup 1.0000x reference)
//
#include <hip/hip_runtime.h>

typedef unsigned short ushort_t;
typedef unsigned int uint_t;

typedef short bf16x8 __attribute__((ext_vector_type(8)));
typedef float f32x4 __attribute__((ext_vector_type(4)));

#define DIM 128
#define BSHIFT 8
#define BNODES 256           // nodes per bucket (1<<BSHIFT)
#define DBINS 64             // degree bins for balance-sort (Poisson(16): max deg ~45)

__device__ __forceinline__ float bf2f(ushort_t u) {
    uint_t x = ((uint_t)u) << 16;
    float f;
    __builtin_memcpy(&f, &x, 4);
    return f;
}

__device__ __forceinline__ ushort_t f2bf(float f) {
    uint_t x;
    __builtin_memcpy(&x, &f, 4);
    uint_t r = (x + 0x7fffu + ((x >> 16) & 1u)) >> 16;
    return (ushort_t)r;
}

// ---------- conversion kernels ----------

__global__ void k_cvt_f32_bf16(const float* __restrict__ in, ushort_t* __restrict__ out, int n4) {
    int i = blockIdx.x * blockDim.x + threadIdx.x;
    if (i < n4) {
        float4 f = ((const float4*)in)[i];
        ushort4 u;
        u.x = f2bf(f.x); u.y = f2bf(f.y); u.z = f2bf(f.z); u.w = f2bf(f.w);
        ((ushort4*)out)[i] = u;
    }
}

// all four weight transposes in one launch: WT[n*128+k] = bf16(W[k*128+n])
__global__ void k_wt4(const float* __restrict__ W0, const float* __restrict__ W1,
                      const float* __restrict__ W2, const float* __restrict__ W3,
                      ushort_t* __restrict__ T0, ushort_t* __restrict__ T1,
                      ushort_t* __restrict__ T2, ushort_t* __restrict__ T3) {
    int i = blockIdx.x * blockDim.x + threadIdx.x;  // 4*16384
    int w = i >> 14, j = i & 16383;
    int n = j >> 7, k = j & 127;
    const float* W = (w == 0) ? W0 : (w == 1) ? W1 : (w == 2) ? W2 : W3;
    ushort_t* T = (w == 0) ? T0 : (w == 1) ? T1 : (w == 2) ? T2 : T3;
    T[j] = f2bf(W[k * DIM + n]);
}

// ---------- CSR build via two-level bucket counting sort ----------
// Device-scope atomics execute at the coherence point on 8-XCD parts and cap
// at ~13 G ops/s; LDS histograms + ~0.2M global reservations avoid that tax.

__global__ __launch_bounds__(256) void k_bhist(const int* __restrict__ dst, int E, int NB,
                                               int* __restrict__ bucketCount) {
    __shared__ int hist[512];
    int t = threadIdx.x;
    for (int b = t; b < NB; b += 256) hist[b] = 0;
    __syncthreads();
    int per = (E + gridDim.x - 1) / gridDim.x;
    int beg = blockIdx.x * per, end = min(beg + per, E);
    for (int i = beg + t; i < end; i += 256)
        atomicAdd(&hist[dst[i] >> BSHIFT], 1);
    __syncthreads();
    for (int b = t; b < NB; b += 256) {
        int v = hist[b];
        if (v) atomicAdd(&bucketCount[b], v);
    }
}

__global__ __launch_bounds__(512) void k_bscan(const int* __restrict__ bucketCount, int NB, int E,
                                               int* __restrict__ bucketBase,
                                               int* __restrict__ bucketCursor,
                                               int* __restrict__ row_ptr, int N) {
    __shared__ int lds[512];
    int t = threadIdx.x;
    int v = (t < NB) ? bucketCount[t] : 0;
    lds[t] = v;
    __syncthreads();
    for (int off = 1; off < 512; off <<= 1) {
        int u = (t >= off) ? lds[t - off] : 0;
        __syncthreads();
        lds[t] += u;
        __syncthreads();
    }
    if (t < NB) {
        int b = lds[t] - v;
        bucketBase[t] = b;
        bucketCursor[t] = b;
    }
    if (t == 0) row_ptr[N] = E;
}

__global__ __launch_bounds__(256) void k_bucketize(const int* __restrict__ src,
                                                   const int* __restrict__ dst, int E, int NB,
                                                   int* __restrict__ bucketCursor,
                                                   uint_t* __restrict__ bebuf) {
    __shared__ int hist[512];
    __shared__ int base[512];
    int t = threadIdx.x;
    for (int b = t; b < NB; b += 256) hist[b] = 0;
    __syncthreads();
    int per = (E + gridDim.x - 1) / gridDim.x;
    int beg = blockIdx.x * per, end = min(beg + per, E);
    for (int i = beg + t; i < end; i += 256)
        atomicAdd(&hist[dst[i] >> BSHIFT], 1);
    __syncthreads();
    for (int b = t; b < NB; b += 256) {
        int v = hist[b];
        base[b] = v ? atomicAdd(&bucketCursor[b], v) : 0;
        hist[b] = 0;
    }
    __syncthreads();
    for (int i = beg + t; i < end; i += 256) {
        int d = dst[i], s = src[i];
        int b = d >> BSHIFT;
        int off = atomicAdd(&hist[b], 1);
        bebuf[base[b] + off] = ((uint_t)(d & (BNODES - 1)) << 24) | (uint_t)s;
    }
}

__global__ __launch_bounds__(256) void k_bcsr(const uint_t* __restrict__ bebuf,
                                              const int* __restrict__ bucketBase,
                                              const int* __restrict__ bucketCount, int N,
                                              int* __restrict__ row_ptr, int* __restrict__ csr) {
    __shared__ int hist[BNODES];
    __shared__ int cur[BNODES];
    int t = threadIdx.x;
    int b = blockIdx.x;
    int ebase = bucketBase[b], cnt = bucketCount[b];
    int nodeBase = b << BSHIFT;
    hist[t] = 0;
    __syncthreads();
    for (int i = t; i < cnt; i += 256)
        atomicAdd(&hist[bebuf[ebase + i] >> 24], 1);
    __syncthreads();
    int v = hist[t];
    for (int off = 1; off < 256; off <<= 1) {
        int u = (t >= off) ? hist[t - off] : 0;
        __syncthreads();
        hist[t] += u;
        __syncthreads();
    }
    int excl = hist[t] - v;
    int node = nodeBase + t;
    if (node < N) row_ptr[node] = ebase + excl;
    cur[t] = excl;
    __syncthreads();
    for (int i = t; i < cnt; i += 256) {
        uint_t e = bebuf[ebase + i];
        int dl = (int)(e >> 24);
        int pos = atomicAdd(&cur[dl], 1);
        csr[ebase + pos] = (int)(e & 0xFFFFFFu);
    }
}

// ---------- degree-balance sort ----------
// Waves in k_agg process 4 nodes (16 lanes each) in lockstep and run for the
// MAX degree of the 4. Poisson(16) degrees: E[max4] ~ 20.4 vs mean 16 -> ~22%
// masked-lane idle. Counting-sort nodes by degree (64 bins) so the 4 nodes
// sharing a wave have equal degree -> uniform trip counts, wave-uniform
// branches. Within-bin order is atomic-race order: harmless, perm is only a
// work assignment (each node computed once, written to its true row).

__global__ __launch_bounds__(256) void k_dhist(const int* __restrict__ rp, int N,
                                               int* __restrict__ dhist) {
    __shared__ int h[DBINS];
    int t = threadIdx.x;
    if (t < DBINS) h[t] = 0;
    __syncthreads();
    int i = blockIdx.x * 256 + t;
    if (i < N) {
        int d = rp[i + 1] - rp[i];
        atomicAdd(&h[min(d, DBINS - 1)], 1);
    }
    __syncthreads();
    if (t < DBINS && h[t]) atomicAdd(&dhist[t], h[t]);
}

__global__ void k_dscan(const int* __restrict__ dhist, int* __restrict__ dcur) {  // 1 block, 64 thr
    __shared__ int l[DBINS];
    int t = threadIdx.x;
    int v = dhist[t];
    l[t] = v;
    __syncthreads();
    for (int off = 1; off < DBINS; off <<= 1) {
        int u = (t >= off) ? l[t - off] : 0;
        __syncthreads();
        l[t] += u;
        __syncthreads();
    }
    dcur[t] = l[t] - v;   // exclusive base
}

__global__ __launch_bounds__(256) void k_dperm(const int* __restrict__ rp, int N,
                                               int* __restrict__ dcur, int* __restrict__ perm) {
    __shared__ int h[DBINS];
    __shared__ int base[DBINS];
    int t = threadIdx.x;
    if (t < DBINS) h[t] = 0;
    __syncthreads();
    int i = blockIdx.x * 256 + t;
    int b = -1;
    if (i < N) {
        int d = rp[i + 1] - rp[i];
        b = min(d, DBINS - 1);
        atomicAdd(&h[b], 1);
    }
    __syncthreads();
    if (t < DBINS) {
        int v = h[t];
        base[t] = v ? atomicAdd(&dcur[t], v) : 0;
        h[t] = 0;
    }
    __syncthreads();
    if (i < N) {
        int off = atomicAdd(&h[b], 1);
        perm[base[b] + off] = i;
    }
}

// ---------- mean aggregation: 16 lanes per node, x4 edge unroll ----------

__device__ __forceinline__ void acc8(float* a, uint4 p) {
    a[0] += bf2f((ushort_t)(p.x & 0xffffu));
    a[1] += bf2f((ushort_t)(p.x >> 16));
    a[2] += bf2f((ushort_t)(p.y & 0xffffu));
    a[3] += bf2f((ushort_t)(p.y >> 16));
    a[4] += bf2f((ushort_t)(p.z & 0xffffu));
    a[5] += bf2f((ushort_t)(p.z >> 16));
    a[6] += bf2f((ushort_t)(p.w & 0xffffu));
    a[7] += bf2f((ushort_t)(p.w >> 16));
}

__global__ __launch_bounds__(256) void k_agg(const ushort_t* __restrict__ X,
                                             const int* __restrict__ row_ptr,
                                             const int* __restrict__ csr,
                                             const int* __restrict__ perm,
                                             ushort_t* __restrict__ out, int n) {
    int g = (int)((blockIdx.x * (unsigned)blockDim.x + threadIdx.x) >> 4);
    if (g >= n) return;
    int node = perm[g];                      // degree-sorted work assignment
    int sl = threadIdx.x & 15;               // sub-lane: 8 bf16 = 16 B of the row
    int beg = row_ptr[node], end = row_ptr[node + 1];
    float a[8] = {0.f, 0.f, 0.f, 0.f, 0.f, 0.f, 0.f, 0.f};

    int e = beg;
    for (; e + 4 <= end; e += 4) {
        int s0 = csr[e + 0], s1 = csr[e + 1], s2 = csr[e + 2], s3 = csr[e + 3];
        uint4 p0 = *(const uint4*)(X + (size_t)s0 * DIM + sl * 8);
        uint4 p1 = *(const uint4*)(X + (size_t)s1 * DIM + sl * 8);
        uint4 p2 = *(const uint4*)(X + (size_t)s2 * DIM + sl * 8);
        uint4 p3 = *(const uint4*)(X + (size_t)s3 * DIM + sl * 8);
        acc8(a, p0); acc8(a, p1); acc8(a, p2); acc8(a, p3);
    }
    for (; e < end; e++) {
        int s = csr[e];
        uint4 p = *(const uint4*)(X + (size_t)s * DIM + sl * 8);
        acc8(a, p);
    }

    int cnt = end - beg;
    float sc = (cnt > 0) ? 1.f / (float)cnt : 0.f;
    uint4 o;
    o.x = (uint_t)f2bf(a[0] * sc) | ((uint_t)f2bf(a[1] * sc) << 16);
    o.y = (uint_t)f2bf(a[2] * sc) | ((uint_t)f2bf(a[3] * sc) << 16);
    o.z = (uint_t)f2bf(a[4] * sc) | ((uint_t)f2bf(a[5] * sc) << 16);
    o.w = (uint_t)f2bf(a[6] * sc) | ((uint_t)f2bf(a[7] * sc) << 16);
    *(uint4*)(out + (size_t)node * DIM + sl * 8) = o;
}

// ---------- fused GEMM with LDS-staged weights ----------
// out = A1*W_l + A2*W_r + b; 32 rows/wave, 128 rows/block (4 waves).
// Both WT tables (64 KB) staged once per block, XOR-swizzled at 16 B-chunk
// granularity: chunk c of row n stored at c ^ (n&15) so ds_read_b128
// fragment reads are <=2-way bank-aliased (free, m136).
// MFMA 16x16x32 bf16 layouts (m89-verified):
//   A frag: lane holds A[m=lane&15][k=quad*8+j]
//   B frag: lane holds B[k=quad*8+j][n=lane&15] = WT[n=lane&15][k=quad*8+j]
//   C/D   : col=lane&15, row=quad*4+reg

template <bool RELU, bool OUT_BF16>
__global__ __launch_bounds__(256) void k_gemm(const ushort_t* __restrict__ A1,
                                              const ushort_t* __restrict__ A2,
                                              const ushort_t* __restrict__ WTl,
                                              const ushort_t* __restrict__ WTr,
                                              const float* __restrict__ bias,
                                              void* __restrict__ Out, int n_waves, int M) {
    __shared__ ushort_t sW[2 * 128 * 128];   // 64 KB
    int t = threadIdx.x;
    int wave = (int)((blockIdx.x * 256u + t) >> 6);
    int lane = t & 63;
    int col = lane & 15;
    int quad = lane >> 4;
    bool active = (wave < n_waves);

    // A-fragment loads issued first: their latency overlaps staging + barrier.
    bf16x8 a[2][8];
    if (active) {
#pragma unroll
        for (int tt = 0; tt < 2; tt++) {
            int arow = wave * 32 + tt * 16 + col;
            const ushort_t* a1p = A1 + (size_t)arow * DIM + quad * 8;
            const ushort_t* a2p = A2 + (size_t)arow * DIM + quad * 8;
#pragma unroll
            for (int ks = 0; ks < 4; ks++) a[tt][ks] = *(const bf16x8*)(a1p + ks * 32);
#pragma unroll
            for (int ks = 0; ks < 4; ks++) a[tt][4 + ks] = *(const bf16x8*)(a2p + ks * 32);
        }
    }

    // stage weights: thread t copies one row (t>>7 selects table, t&127 the row)
    {
        int tab = t >> 7, row = t & 127;
        const ushort_t* g = (tab ? WTr : WTl) + (size_t)row * 128;
        ushort_t* d = sW + (size_t)t * 128;
        int sw = row & 15;
#pragma unroll
        for (int c = 0; c < 16; c++) {
            uint4 v = *(const uint4*)(g + c * 8);
            *(uint4*)(d + ((c ^ sw) * 8)) = v;
        }
    }
    __syncthreads();
    if (!active) return;

    f32x4 acc[2][8];
#pragma unroll
    for (int tt = 0; tt < 2; tt++)
#pragma unroll
        for (int nt = 0; nt < 8; nt++) acc[tt][nt] = (f32x4){0.f, 0.f, 0.f, 0.f};

    const ushort_t* sWl = sW;
    const ushort_t* sWr = sW + 128 * 128;
#pragma unroll
    for (int nt = 0; nt < 8; nt++) {
        int row = nt * 16 + col;
        const ushort_t* bl = sWl + (size_t)row * 128;
        const ushort_t* br = sWr + (size_t)row * 128;
#pragma unroll
        for (int ks = 0; ks < 4; ks++) {
            bf16x8 b = *(const bf16x8*)(bl + (((ks * 4 + quad) ^ col) * 8));
            acc[0][nt] = __builtin_amdgcn_mfma_f32_16x16x32_bf16(a[0][ks], b, acc[0][nt], 0, 0, 0);
            acc[1][nt] = __builtin_amdgcn_mfma_f32_16x16x32_bf16(a[1][ks], b, acc[1][nt], 0, 0, 0);
        }
#pragma unroll
        for (int ks = 0; ks < 4; ks++) {
            bf16x8 b = *(const bf16x8*)(br + (((ks * 4 + quad) ^ col) * 8));
            acc[0][nt] = __builtin_amdgcn_mfma_f32_16x16x32_bf16(a[0][4 + ks], b, acc[0][nt], 0, 0, 0);
            acc[1][nt] = __builtin_amdgcn_mfma_f32_16x16x32_bf16(a[1][4 + ks], b, acc[1][nt], 0, 0, 0);
        }
    }

#pragma unroll
    for (int tt = 0; tt < 2; tt++)
#pragma unroll
        for (int nt = 0; nt < 8; nt++) {
            int c = nt * 16 + col;
            float bv = bias[c];
#pragma unroll
            for (int r = 0; r < 4; r++) {
                int m = wave * 32 + tt * 16 + quad * 4 + r;
                if (m < M) {
                    float v = acc[tt][nt][r] + bv;
                    if (RELU) v = v > 0.f ? v : 0.f;
                    if (OUT_BF16)
                        ((ushort_t*)Out)[(size_t)m * DIM + c] = f2bf(v);
                    else
                        ((float*)Out)[(size_t)m * DIM + c] = v;
                }
            }
        }
}

// ---------- host ----------

extern "C" void kernel_launch(void* const* d_in, const int* in_sizes, int n_in,
                              void* d_out, int out_size, void* d_ws, size_t ws_size,
                              hipStream_t stream) {
    const int N = in_sizes[0] / DIM;   // 100000
    const int E = in_sizes[1] / 2;     // 1600000
    const int NB = (N + BNODES - 1) >> BSHIFT;   // 391 buckets

    const float* x   = (const float*)d_in[0];
    const int*   ei  = (const int*)d_in[1];
    const int*   src = ei;
    const int*   dst = ei + E;
    const float* W1l = (const float*)d_in[2];
    const float* b1  = (const float*)d_in[3];
    const float* W1r = (const float*)d_in[4];
    const float* W2l = (const float*)d_in[5];
    const float* b2  = (const float*)d_in[6];
    const float* W2r = (const float*)d_in[7];
    float* out = (float*)d_out;

    char* ws = (char*)d_ws;
    size_t off = 0;
    auto alloc = [&](size_t bytes) -> char* {
        char* p = ws + off;
        off = (off + bytes + 255) & ~(size_t)255;
        return p;
    };

    int*      bucketCount  = (int*)alloc((size_t)NB * 4);
    int*      dhist        = (int*)alloc((size_t)DBINS * 4);   // adjacent to bucketCount: one memset
    int*      dcur         = (int*)alloc((size_t)DBINS * 4);   // fully written by k_dscan
    int*      bucketBase   = (int*)alloc((size_t)NB * 4);
    int*      bucketCursor = (int*)alloc((size_t)NB * 4);
    int*      row_ptr      = (int*)alloc((size_t)(N + 1) * 4);
    int*      csr          = (int*)alloc((size_t)E * 4);
    uint_t*   bebuf        = (uint_t*)alloc((size_t)E * 4);
    size_t    fpad         = (size_t)32 * DIM * 2;   // tile-padding for MFMA A loads
    ushort_t* xb           = (ushort_t*)alloc((size_t)N * DIM * 2 + fpad);
    ushort_t* hb           = (ushort_t*)alloc((size_t)N * DIM * 2 + fpad);
    ushort_t* aggb         = (ushort_t*)alloc((size_t)N * DIM * 2 + fpad);
    ushort_t* wt1l         = (ushort_t*)alloc((size_t)DIM * DIM * 2);
    ushort_t* wt1r         = (ushort_t*)alloc((size_t)DIM * DIM * 2);
    ushort_t* wt2l         = (ushort_t*)alloc((size_t)DIM * DIM * 2);
    ushort_t* wt2r         = (ushort_t*)alloc((size_t)DIM * DIM * 2);
    int*      perm         = (int*)bebuf;   // bebuf is dead after k_bcsr; reuse as perm

    // zero bucket histogram + degree histogram in one shot (ws is poisoned each call)
    hipMemsetAsync(bucketCount, 0, (size_t)((char*)dhist - (char*)bucketCount) + DBINS * 4, stream);

    // x -> bf16
    {
        int n4 = N * DIM / 4;
        k_cvt_f32_bf16<<<dim3((n4 + 255) / 256), dim3(256), 0, stream>>>(x, xb, n4);
    }
    // weights -> transposed bf16 (single launch)
    k_wt4<<<dim3(4 * DIM * DIM / 256), dim3(256), 0, stream>>>(W1l, W1r, W2l, W2r,
                                                               wt1l, wt1r, wt2l, wt2r);
    // CSR build: bucket counting sort
    k_bhist<<<dim3(256), dim3(256), 0, stream>>>(dst, E, NB, bucketCount);
    k_bscan<<<dim3(1), dim3(512), 0, stream>>>(bucketCount, NB, E, bucketBase, bucketCursor, row_ptr, N);
    k_bucketize<<<dim3(256), dim3(256), 0, stream>>>(src, dst, E, NB, bucketCursor, bebuf);
    k_bcsr<<<dim3(NB), dim3(256), 0, stream>>>(bebuf, bucketBase, bucketCount, N, row_ptr, csr);

    // degree-balance permutation (bebuf dead from here; perm aliases it)
    const int nblk = (N + 255) / 256;
    k_dhist<<<dim3(nblk), dim3(256), 0, stream>>>(row_ptr, N, dhist);
    k_dscan<<<dim3(1), dim3(DBINS), 0, stream>>>(dhist, dcur);
    k_dperm<<<dim3(nblk), dim3(256), 0, stream>>>(row_ptr, N, dcur, perm);

    const int n_waves = (N + 31) / 32;                          // 3125 (32 rows/wave)
    dim3 gemm_grid((n_waves + 3) / 4), gemm_blk(256);
    dim3 agg_grid((N + 15) / 16), agg_blk(256);                 // 16 nodes/block (16 lanes/node)

    // layer 1
    k_agg<<<agg_grid, agg_blk, 0, stream>>>(xb, row_ptr, csr, perm, aggb, N);
    k_gemm<true, true><<<gemm_grid, gemm_blk, 0, stream>>>(aggb, xb, wt1l, wt1r, b1, hb, n_waves, N);
    // layer 2
    k_agg<<<agg_grid, agg_blk, 0, stream>>>(hb, row_ptr, csr, perm, aggb, N);
    k_gemm<false, false><<<gemm_grid, gemm_blk, 0, stream>>>(aggb, hb, wt2l, wt2r, b2, out, n_waves, N);

    (void)n_in; (void)out_size; (void)ws_size;
}

// Round 2
// 367.133 us; speedup vs baseline: 1.0215x; 1.0215x over previous
//
#include <hip/hip_runtime.h>

typedef unsigned short ushort_t;
typedef unsigned int uint_t;

typedef short bf16x8 __attribute__((ext_vector_type(8)));
typedef float f32x4 __attribute__((ext_vector_type(4)));

#define DIM 128
#define BSHIFT 8
#define BNODES 256           // nodes per bucket (1<<BSHIFT)
#define DBINS 64             // degree bins for balance-sort (Poisson(16): max deg ~45)

__device__ __forceinline__ float bf2f(ushort_t u) {
    uint_t x = ((uint_t)u) << 16;
    float f;
    __builtin_memcpy(&f, &x, 4);
    return f;
}

__device__ __forceinline__ ushort_t f2bf(float f) {
    uint_t x;
    __builtin_memcpy(&x, &f, 4);
    uint_t r = (x + 0x7fffu + ((x >> 16) & 1u)) >> 16;
    return (ushort_t)r;
}

// ---------- prep: x->bf16 cast + all four weight transposes, ONE launch ----------

__global__ __launch_bounds__(256) void k_prep(const float* __restrict__ x, ushort_t* __restrict__ xb,
                                              int n4,
                                              const float* __restrict__ W0, const float* __restrict__ W1,
                                              const float* __restrict__ W2, const float* __restrict__ W3,
                                              ushort_t* __restrict__ T0, ushort_t* __restrict__ T1,
                                              ushort_t* __restrict__ T2, ushort_t* __restrict__ T3) {
    int i = blockIdx.x * 256 + threadIdx.x;
    if (i < n4) {
        float4 f = ((const float4*)x)[i];
        ushort4 u;
        u.x = f2bf(f.x); u.y = f2bf(f.y); u.z = f2bf(f.z); u.w = f2bf(f.w);
        ((ushort4*)xb)[i] = u;
    } else {
        int j = i - n4;                       // 0 .. 4*16384-1
        if (j < 4 * DIM * DIM) {
            int w = j >> 14; j &= 16383;
            int n = j >> 7, k = j & 127;
            const float* W = (w == 0) ? W0 : (w == 1) ? W1 : (w == 2) ? W2 : W3;
            ushort_t* T = (w == 0) ? T0 : (w == 1) ? T1 : (w == 2) ? T2 : T3;
            T[j] = f2bf(W[k * DIM + n]);      // WT[n*128+k] = bf16(W[k*128+n])
        }
    }
}

// ---------- CSR build via two-level bucket counting sort ----------
// Device-scope atomics execute at the coherence point on 8-XCD parts and cap
// at ~13 G ops/s; LDS histograms + ~0.2M global reservations avoid that tax.

__global__ __launch_bounds__(256) void k_bhist(const int* __restrict__ dst, int E, int NB,
                                               int* __restrict__ bucketCount) {
    __shared__ int hist[512];
    int t = threadIdx.x;
    for (int b = t; b < NB; b += 256) hist[b] = 0;
    __syncthreads();
    int per = (E + gridDim.x - 1) / gridDim.x;
    int beg = blockIdx.x * per, end = min(beg + per, E);
    for (int i = beg + t; i < end; i += 256)
        atomicAdd(&hist[dst[i] >> BSHIFT], 1);
    __syncthreads();
    for (int b = t; b < NB; b += 256) {
        int v = hist[b];
        if (v) atomicAdd(&bucketCount[b], v);
    }
}

__global__ __launch_bounds__(512) void k_bscan(const int* __restrict__ bucketCount, int NB, int E,
                                               int* __restrict__ bucketBase,
                                               int* __restrict__ bucketCursor,
                                               int* __restrict__ row_ptr, int N) {
    __shared__ int lds[512];
    int t = threadIdx.x;
    int v = (t < NB) ? bucketCount[t] : 0;
    lds[t] = v;
    __syncthreads();
    for (int off = 1; off < 512; off <<= 1) {
        int u = (t >= off) ? lds[t - off] : 0;
        __syncthreads();
        lds[t] += u;
        __syncthreads();
    }
    if (t < NB) {
        int b = lds[t] - v;
        bucketBase[t] = b;
        bucketCursor[t] = b;
    }
    if (t == 0) row_ptr[N] = E;
}

__global__ __launch_bounds__(256) void k_bucketize(const int* __restrict__ src,
                                                   const int* __restrict__ dst, int E, int NB,
                                                   int* __restrict__ bucketCursor,
                                                   uint_t* __restrict__ bebuf) {
    __shared__ int hist[512];
    __shared__ int base[512];
    int t = threadIdx.x;
    for (int b = t; b < NB; b += 256) hist[b] = 0;
    __syncthreads();
    int per = (E + gridDim.x - 1) / gridDim.x;
    int beg = blockIdx.x * per, end = min(beg + per, E);
    for (int i = beg + t; i < end; i += 256)
        atomicAdd(&hist[dst[i] >> BSHIFT], 1);
    __syncthreads();
    for (int b = t; b < NB; b += 256) {
        int v = hist[b];
        base[b] = v ? atomicAdd(&bucketCursor[b], v) : 0;
        hist[b] = 0;
    }
    __syncthreads();
    for (int i = beg + t; i < end; i += 256) {
        int d = dst[i], s = src[i];
        int b = d >> BSHIFT;
        int off = atomicAdd(&hist[b], 1);
        bebuf[base[b] + off] = ((uint_t)(d & (BNODES - 1)) << 24) | (uint_t)s;
    }
}

// k_bcsr also folds the degree histogram for the balance-sort: after the count
// phase, hist[t] IS deg(node nodeBase+t) — the separate k_dhist pass over
// row_ptr was redundant work + a launch.
__global__ __launch_bounds__(256) void k_bcsr(const uint_t* __restrict__ bebuf,
                                              const int* __restrict__ bucketBase,
                                              const int* __restrict__ bucketCount, int N,
                                              int* __restrict__ row_ptr, int* __restrict__ csr,
                                              int* __restrict__ dhist) {
    __shared__ int hist[BNODES];
    __shared__ int cur[BNODES];
    __shared__ int dh[DBINS];
    int t = threadIdx.x;
    int b = blockIdx.x;
    int ebase = bucketBase[b], cnt = bucketCount[b];
    int nodeBase = b << BSHIFT;
    hist[t] = 0;
    if (t < DBINS) dh[t] = 0;
    __syncthreads();
    for (int i = t; i < cnt; i += 256)
        atomicAdd(&hist[bebuf[ebase + i] >> 24], 1);
    __syncthreads();
    int v = hist[t];
    int node = nodeBase + t;
    if (node < N) atomicAdd(&dh[min(v, DBINS - 1)], 1);
    for (int off = 1; off < 256; off <<= 1) {
        int u = (t >= off) ? hist[t - off] : 0;
        __syncthreads();
        hist[t] += u;
        __syncthreads();
    }
    int excl = hist[t] - v;
    if (node < N) row_ptr[node] = ebase + excl;
    cur[t] = excl;
    __syncthreads();
    for (int i = t; i < cnt; i += 256) {
        uint_t e = bebuf[ebase + i];
        int dl = (int)(e >> 24);
        int pos = atomicAdd(&cur[dl], 1);
        csr[ebase + pos] = (int)(e & 0xFFFFFFu);
    }
    __syncthreads();
    if (t < DBINS) {
        int c = dh[t];
        if (c) atomicAdd(&dhist[t], c);
    }
}

// ---------- degree-balance sort (scan + perm; hist folded into k_bcsr) ----------
// Waves in k_agg process 4 nodes (16 lanes each) in lockstep and run for the
// MAX degree of the 4; equal-degree grouping makes trip counts wave-uniform.

__global__ void k_dscan(const int* __restrict__ dhist, int* __restrict__ dcur) {  // 1 block, 64 thr
    __shared__ int l[DBINS];
    int t = threadIdx.x;
    int v = dhist[t];
    l[t] = v;
    __syncthreads();
    for (int off = 1; off < DBINS; off <<= 1) {
        int u = (t >= off) ? l[t - off] : 0;
        __syncthreads();
        l[t] += u;
        __syncthreads();
    }
    dcur[t] = l[t] - v;   // exclusive base
}

__global__ __launch_bounds__(256) void k_dperm(const int* __restrict__ rp, int N,
                                               int* __restrict__ dcur, int* __restrict__ perm) {
    __shared__ int h[DBINS];
    __shared__ int base[DBINS];
    int t = threadIdx.x;
    if (t < DBINS) h[t] = 0;
    __syncthreads();
    int i = blockIdx.x * 256 + t;
    int b = -1;
    if (i < N) {
        int d = rp[i + 1] - rp[i];
        b = min(d, DBINS - 1);
        atomicAdd(&h[b], 1);
    }
    __syncthreads();
    if (t < DBINS) {
        int v = h[t];
        base[t] = v ? atomicAdd(&dcur[t], v) : 0;
        h[t] = 0;
    }
    __syncthreads();
    if (i < N) {
        int off = atomicAdd(&h[b], 1);
        perm[base[b] + off] = i;
    }
}

// ---------- mean aggregation: 16 lanes per node, x8 edge unroll ----------
// Latency-bound gather (3.1 TB/s fill vs >10 TB/s L3 ceiling, VALUBusy 22%):
// 8 row-loads in flight per wave + 2-op/pair bf16 unpack (lo = u<<16,
// hi = u & 0xffff0000 — bitwise identical to scalar bf2f).

__device__ __forceinline__ void acc8(float* a, uint4 p) {
    union { uint_t u; float f; } c;
    c.u = p.x << 16;         a[0] += c.f;
    c.u = p.x & 0xffff0000u; a[1] += c.f;
    c.u = p.y << 16;         a[2] += c.f;
    c.u = p.y & 0xffff0000u; a[3] += c.f;
    c.u = p.z << 16;         a[4] += c.f;
    c.u = p.z & 0xffff0000u; a[5] += c.f;
    c.u = p.w << 16;         a[6] += c.f;
    c.u = p.w & 0xffff0000u; a[7] += c.f;
}

__global__ __launch_bounds__(256) void k_agg(const ushort_t* __restrict__ X,
                                             const int* __restrict__ row_ptr,
                                             const int* __restrict__ csr,
                                             const int* __restrict__ perm,
                                             ushort_t* __restrict__ out, int n) {
    int g = (int)((blockIdx.x * (unsigned)blockDim.x + threadIdx.x) >> 4);
    if (g >= n) return;
    int node = perm[g];                      // degree-sorted work assignment
    int sl = threadIdx.x & 15;               // sub-lane: 8 bf16 = 16 B of the row
    int beg = row_ptr[node], end = row_ptr[node + 1];
    float a[8] = {0.f, 0.f, 0.f, 0.f, 0.f, 0.f, 0.f, 0.f};

    int e = beg;
    for (; e + 8 <= end; e += 8) {
        uint4 p[8];
#pragma unroll
        for (int j = 0; j < 8; j++) {
            int s = csr[e + j];
            p[j] = *(const uint4*)(X + (size_t)s * DIM + sl * 8);
        }
#pragma unroll
        for (int j = 0; j < 8; j++) acc8(a, p[j]);
    }
    if (e + 4 <= end) {
        uint4 p[4];
#pragma unroll
        for (int j = 0; j < 4; j++) {
            int s = csr[e + j];
            p[j] = *(const uint4*)(X + (size_t)s * DIM + sl * 8);
        }
#pragma unroll
        for (int j = 0; j < 4; j++) acc8(a, p[j]);
        e += 4;
    }
    for (; e < end; e++) {
        int s = csr[e];
        uint4 p = *(const uint4*)(X + (size_t)s * DIM + sl * 8);
        acc8(a, p);
    }

    int cnt = end - beg;
    float sc = (cnt > 0) ? 1.f / (float)cnt : 0.f;
    uint4 o;
    o.x = (uint_t)f2bf(a[0] * sc) | ((uint_t)f2bf(a[1] * sc) << 16);
    o.y = (uint_t)f2bf(a[2] * sc) | ((uint_t)f2bf(a[3] * sc) << 16);
    o.z = (uint_t)f2bf(a[4] * sc) | ((uint_t)f2bf(a[5] * sc) << 16);
    o.w = (uint_t)f2bf(a[6] * sc) | ((uint_t)f2bf(a[7] * sc) << 16);
    *(uint4*)(out + (size_t)node * DIM + sl * 8) = o;
}

// ---------- fused GEMM with LDS-staged weights ----------
// out = A1*W_l + A2*W_r + b; 32 rows/wave, 128 rows/block (4 waves).
// Both WT tables (64 KB) staged once per block, XOR-swizzled at 16 B-chunk
// granularity: chunk c of row n stored at c ^ (n&15) so ds_read_b128
// fragment reads are <=2-way bank-aliased (free, m136).
// MFMA 16x16x32 bf16 layouts (m89-verified):
//   A frag: lane holds A[m=lane&15][k=quad*8+j]
//   B frag: lane holds B[k=quad*8+j][n=lane&15] = WT[n=lane&15][k=quad*8+j]
//   C/D   : col=lane&15, row=quad*4+reg

template <bool RELU, bool OUT_BF16>
__global__ __launch_bounds__(256) void k_gemm(const ushort_t* __restrict__ A1,
                                              const ushort_t* __restrict__ A2,
                                              const ushort_t* __restrict__ WTl,
                                              const ushort_t* __restrict__ WTr,
                                              const float* __restrict__ bias,
                                              void* __restrict__ Out, int n_waves, int M) {
    __shared__ ushort_t sW[2 * 128 * 128];   // 64 KB
    int t = threadIdx.x;
    int wave = (int)((blockIdx.x * 256u + t) >> 6);
    int lane = t & 63;
    int col = lane & 15;
    int quad = lane >> 4;
    bool active = (wave < n_waves);

    // A-fragment loads issued first: their latency overlaps staging + barrier.
    bf16x8 a[2][8];
    if (active) {
#pragma unroll
        for (int tt = 0; tt < 2; tt++) {
            int arow = wave * 32 + tt * 16 + col;
            const ushort_t* a1p = A1 + (size_t)arow * DIM + quad * 8;
            const ushort_t* a2p = A2 + (size_t)arow * DIM + quad * 8;
#pragma unroll
            for (int ks = 0; ks < 4; ks++) a[tt][ks] = *(const bf16x8*)(a1p + ks * 32);
#pragma unroll
            for (int ks = 0; ks < 4; ks++) a[tt][4 + ks] = *(const bf16x8*)(a2p + ks * 32);
        }
    }

    // stage weights: thread t copies one row (t>>7 selects table, t&127 the row)
    {
        int tab = t >> 7, row = t & 127;
        const ushort_t* g = (tab ? WTr : WTl) + (size_t)row * 128;
        ushort_t* d = sW + (size_t)t * 128;
        int sw = row & 15;
#pragma unroll
        for (int c = 0; c < 16; c++) {
            uint4 v = *(const uint4*)(g + c * 8);
            *(uint4*)(d + ((c ^ sw) * 8)) = v;
        }
    }
    __syncthreads();
    if (!active) return;

    f32x4 acc[2][8];
#pragma unroll
    for (int tt = 0; tt < 2; tt++)
#pragma unroll
        for (int nt = 0; nt < 8; nt++) acc[tt][nt] = (f32x4){0.f, 0.f, 0.f, 0.f};

    const ushort_t* sWl = sW;
    const ushort_t* sWr = sW + 128 * 128;
#pragma unroll
    for (int nt = 0; nt < 8; nt++) {
        int row = nt * 16 + col;
        const ushort_t* bl = sWl + (size_t)row * 128;
        const ushort_t* br = sWr + (size_t)row * 128;
#pragma unroll
        for (int ks = 0; ks < 4; ks++) {
            bf16x8 b = *(const bf16x8*)(bl + (((ks * 4 + quad) ^ col) * 8));
            acc[0][nt] = __builtin_amdgcn_mfma_f32_16x16x32_bf16(a[0][ks], b, acc[0][nt], 0, 0, 0);
            acc[1][nt] = __builtin_amdgcn_mfma_f32_16x16x32_bf16(a[1][ks], b, acc[1][nt], 0, 0, 0);
        }
#pragma unroll
        for (int ks = 0; ks < 4; ks++) {
            bf16x8 b = *(const bf16x8*)(br + (((ks * 4 + quad) ^ col) * 8));
            acc[0][nt] = __builtin_amdgcn_mfma_f32_16x16x32_bf16(a[0][4 + ks], b, acc[0][nt], 0, 0, 0);
            acc[1][nt] = __builtin_amdgcn_mfma_f32_16x16x32_bf16(a[1][4 + ks], b, acc[1][nt], 0, 0, 0);
        }
    }

#pragma unroll
    for (int tt = 0; tt < 2; tt++)
#pragma unroll
        for (int nt = 0; nt < 8; nt++) {
            int c = nt * 16 + col;
            float bv = bias[c];
#pragma unroll
            for (int r = 0; r < 4; r++) {
                int m = wave * 32 + tt * 16 + quad * 4 + r;
                if (m < M) {
                    float v = acc[tt][nt][r] + bv;
                    if (RELU) v = v > 0.f ? v : 0.f;
                    if (OUT_BF16)
                        ((ushort_t*)Out)[(size_t)m * DIM + c] = f2bf(v);
                    else
                        ((float*)Out)[(size_t)m * DIM + c] = v;
                }
            }
        }
}

// ---------- host ----------

extern "C" void kernel_launch(void* const* d_in, const int* in_sizes, int n_in,
                              void* d_out, int out_size, void* d_ws, size_t ws_size,
                              hipStream_t stream) {
    const int N = in_sizes[0] / DIM;   // 100000
    const int E = in_sizes[1] / 2;     // 1600000
    const int NB = (N + BNODES - 1) >> BSHIFT;   // 391 buckets

    const float* x   = (const float*)d_in[0];
    const int*   ei  = (const int*)d_in[1];
    const int*   src = ei;
    const int*   dst = ei + E;
    const float* W1l = (const float*)d_in[2];
    const float* b1  = (const float*)d_in[3];
    const float* W1r = (const float*)d_in[4];
    const float* W2l = (const float*)d_in[5];
    const float* b2  = (const float*)d_in[6];
    const float* W2r = (const float*)d_in[7];
    float* out = (float*)d_out;

    char* ws = (char*)d_ws;
    size_t off = 0;
    auto alloc = [&](size_t bytes) -> char* {
        char* p = ws + off;
        off = (off + bytes + 255) & ~(size_t)255;
        return p;
    };

    int*      bucketCount  = (int*)alloc((size_t)NB * 4);
    int*      dhist        = (int*)alloc((size_t)DBINS * 4);   // adjacent to bucketCount: one memset
    int*      dcur         = (int*)alloc((size_t)DBINS * 4);   // fully written by k_dscan
    int*      bucketBase   = (int*)alloc((size_t)NB * 4);
    int*      bucketCursor = (int*)alloc((size_t)NB * 4);
    int*      row_ptr      = (int*)alloc((size_t)(N + 1) * 4);
    int*      csr          = (int*)alloc((size_t)E * 4);
    uint_t*   bebuf        = (uint_t*)alloc((size_t)E * 4);
    size_t    fpad         = (size_t)32 * DIM * 2;   // tile-padding for MFMA A loads
    ushort_t* xb           = (ushort_t*)alloc((size_t)N * DIM * 2 + fpad);
    ushort_t* hb           = (ushort_t*)alloc((size_t)N * DIM * 2 + fpad);
    ushort_t* aggb         = (ushort_t*)alloc((size_t)N * DIM * 2 + fpad);
    ushort_t* wt1l         = (ushort_t*)alloc((size_t)DIM * DIM * 2);
    ushort_t* wt1r         = (ushort_t*)alloc((size_t)DIM * DIM * 2);
    ushort_t* wt2l         = (ushort_t*)alloc((size_t)DIM * DIM * 2);
    ushort_t* wt2r         = (ushort_t*)alloc((size_t)DIM * DIM * 2);
    int*      perm         = (int*)bebuf;   // bebuf is dead after k_bcsr; reuse as perm

    // zero bucket histogram + degree histogram in one shot (ws is poisoned each call)
    hipMemsetAsync(bucketCount, 0, (size_t)((char*)dhist - (char*)bucketCount) + DBINS * 4, stream);

    // x -> bf16 cast + weight transposes, single launch
    {
        int n4 = N * DIM / 4;
        int total = n4 + 4 * DIM * DIM;
        k_prep<<<dim3((total + 255) / 256), dim3(256), 0, stream>>>(
            x, xb, n4, W1l, W1r, W2l, W2r, wt1l, wt1r, wt2l, wt2r);
    }
    // CSR build: bucket counting sort (degree histogram folded into k_bcsr)
    k_bhist<<<dim3(256), dim3(256), 0, stream>>>(dst, E, NB, bucketCount);
    k_bscan<<<dim3(1), dim3(512), 0, stream>>>(bucketCount, NB, E, bucketBase, bucketCursor, row_ptr, N);
    k_bucketize<<<dim3(256), dim3(256), 0, stream>>>(src, dst, E, NB, bucketCursor, bebuf);
    k_bcsr<<<dim3(NB), dim3(256), 0, stream>>>(bebuf, bucketBase, bucketCount, N, row_ptr, csr, dhist);

    // degree-balance permutation (bebuf dead from here; perm aliases it)
    const int nblk = (N + 255) / 256;
    k_dscan<<<dim3(1), dim3(DBINS), 0, stream>>>(dhist, dcur);
    k_dperm<<<dim3(nblk), dim3(256), 0, stream>>>(row_ptr, N, dcur, perm);

    const int n_waves = (N + 31) / 32;                          // 3125 (32 rows/wave)
    dim3 gemm_grid((n_waves + 3) / 4), gemm_blk(256);
    dim3 agg_grid((N + 15) / 16), agg_blk(256);                 // 16 nodes/block (16 lanes/node)

    // layer 1
    k_agg<<<agg_grid, agg_blk, 0, stream>>>(xb, row_ptr, csr, perm, aggb, N);
    k_gemm<true, true><<<gemm_grid, gemm_blk, 0, stream>>>(aggb, xb, wt1l, wt1r, b1, hb, n_waves, N);
    // layer 2
    k_agg<<<agg_grid, agg_blk, 0, stream>>>(hb, row_ptr, csr, perm, aggb, N);
    k_gemm<false, false><<<gemm_grid, gemm_blk, 0, stream>>>(aggb, hb, wt2l, wt2r, b2, out, n_waves, N);

    (void)n_in; (void)out_size; (void)ws_size;
}

// Round 3
// 354.628 us; speedup vs baseline: 1.0575x; 1.0353x over previous
//
#include <hip/hip_runtime.h>

typedef unsigned short ushort_t;
typedef unsigned int uint_t;

typedef short bf16x8 __attribute__((ext_vector_type(8)));
typedef float f32x4 __attribute__((ext_vector_type(4)));

#define DIM 128
#define BSHIFT 8
#define BNODES 256           // nodes per bucket (1<<BSHIFT)
#define DBINS 64             // degree bins for balance-sort (Poisson(16): max deg ~45)

__device__ __forceinline__ float bf2f(ushort_t u) {
    uint_t x = ((uint_t)u) << 16;
    float f;
    __builtin_memcpy(&f, &x, 4);
    return f;
}

__device__ __forceinline__ ushort_t f2bf(float f) {
    uint_t x;
    __builtin_memcpy(&x, &f, 4);
    uint_t r = (x + 0x7fffu + ((x >> 16) & 1u)) >> 16;
    return (ushort_t)r;
}

// ---------- prep (x->bf16 + weight transposes) + bhist, ONE launch ----------
// Blocks [0, prepBlocks) do the casts; blocks [prepBlocks, prepBlocks+256) do
// the dst bucket histogram. Independent inputs, so fusion is safe; saves a
// launch + gap.

__global__ __launch_bounds__(256) void k_prep_bhist(
        const float* __restrict__ x, ushort_t* __restrict__ xb, int n4,
        const float* __restrict__ W0, const float* __restrict__ W1,
        const float* __restrict__ W2, const float* __restrict__ W3,
        ushort_t* __restrict__ T0, ushort_t* __restrict__ T1,
        ushort_t* __restrict__ T2, ushort_t* __restrict__ T3,
        const int* __restrict__ dst, int E, int NB, int* __restrict__ bucketCount,
        int prepBlocks) {
    if ((int)blockIdx.x >= prepBlocks) {
        __shared__ int hist[512];
        int blk = blockIdx.x - prepBlocks;   // 0..255
        int t = threadIdx.x;
        for (int b = t; b < NB; b += 256) hist[b] = 0;
        __syncthreads();
        int per = (E + 255) / 256;
        int beg = blk * per, end = min(beg + per, E);
        for (int i = beg + t; i < end; i += 256)
            atomicAdd(&hist[dst[i] >> BSHIFT], 1);
        __syncthreads();
        for (int b = t; b < NB; b += 256) {
            int v = hist[b];
            if (v) atomicAdd(&bucketCount[b], v);
        }
        return;
    }
    int i = blockIdx.x * 256 + threadIdx.x;
    if (i < n4) {
        float4 f = ((const float4*)x)[i];
        ushort4 u;
        u.x = f2bf(f.x); u.y = f2bf(f.y); u.z = f2bf(f.z); u.w = f2bf(f.w);
        ((ushort4*)xb)[i] = u;
    } else {
        int j = i - n4;                       // 0 .. 4*16384-1
        if (j < 4 * DIM * DIM) {
            int w = j >> 14; j &= 16383;
            int n = j >> 7, k = j & 127;
            const float* W = (w == 0) ? W0 : (w == 1) ? W1 : (w == 2) ? W2 : W3;
            ushort_t* T = (w == 0) ? T0 : (w == 1) ? T1 : (w == 2) ? T2 : T3;
            T[j] = f2bf(W[k * DIM + n]);      // WT[n*128+k] = bf16(W[k*128+n])
        }
    }
}

// ---------- CSR build via two-level bucket counting sort ----------

__global__ __launch_bounds__(512) void k_bscan(const int* __restrict__ bucketCount, int NB, int E,
                                               int* __restrict__ bucketBase,
                                               int* __restrict__ bucketCursor,
                                               int* __restrict__ row_ptr, int N) {
    __shared__ int lds[512];
    int t = threadIdx.x;
    int v = (t < NB) ? bucketCount[t] : 0;
    lds[t] = v;
    __syncthreads();
    for (int off = 1; off < 512; off <<= 1) {
        int u = (t >= off) ? lds[t - off] : 0;
        __syncthreads();
        lds[t] += u;
        __syncthreads();
    }
    if (t < NB) {
        int b = lds[t] - v;
        bucketBase[t] = b;
        bucketCursor[t] = b;
    }
    if (t == 0) row_ptr[N] = E;
}

__global__ __launch_bounds__(256) void k_bucketize(const int* __restrict__ src,
                                                   const int* __restrict__ dst, int E, int NB,
                                                   int* __restrict__ bucketCursor,
                                                   uint_t* __restrict__ bebuf) {
    __shared__ int hist[512];
    __shared__ int base[512];
    int t = threadIdx.x;
    for (int b = t; b < NB; b += 256) hist[b] = 0;
    __syncthreads();
    int per = (E + gridDim.x - 1) / gridDim.x;
    int beg = blockIdx.x * per, end = min(beg + per, E);
    for (int i = beg + t; i < end; i += 256)
        atomicAdd(&hist[dst[i] >> BSHIFT], 1);
    __syncthreads();
    for (int b = t; b < NB; b += 256) {
        int v = hist[b];
        base[b] = v ? atomicAdd(&bucketCursor[b], v) : 0;
        hist[b] = 0;
    }
    __syncthreads();
    for (int i = beg + t; i < end; i += 256) {
        int d = dst[i], s = src[i];
        int b = d >> BSHIFT;
        int off = atomicAdd(&hist[b], 1);
        bebuf[base[b] + off] = ((uint_t)(d & (BNODES - 1)) << 24) | (uint_t)s;
    }
}

// k_bcsr also folds the degree histogram for the balance-sort: after the count
// phase, hist[t] IS deg(node nodeBase+t).
__global__ __launch_bounds__(256) void k_bcsr(const uint_t* __restrict__ bebuf,
                                              const int* __restrict__ bucketBase,
                                              const int* __restrict__ bucketCount, int N,
                                              int* __restrict__ row_ptr, int* __restrict__ csr,
                                              int* __restrict__ dhist) {
    __shared__ int hist[BNODES];
    __shared__ int cur[BNODES];
    __shared__ int dh[DBINS];
    int t = threadIdx.x;
    int b = blockIdx.x;
    int ebase = bucketBase[b], cnt = bucketCount[b];
    int nodeBase = b << BSHIFT;
    hist[t] = 0;
    if (t < DBINS) dh[t] = 0;
    __syncthreads();
    for (int i = t; i < cnt; i += 256)
        atomicAdd(&hist[bebuf[ebase + i] >> 24], 1);
    __syncthreads();
    int v = hist[t];
    int node = nodeBase + t;
    if (node < N) atomicAdd(&dh[min(v, DBINS - 1)], 1);
    for (int off = 1; off < 256; off <<= 1) {
        int u = (t >= off) ? hist[t - off] : 0;
        __syncthreads();
        hist[t] += u;
        __syncthreads();
    }
    int excl = hist[t] - v;
    if (node < N) row_ptr[node] = ebase + excl;
    cur[t] = excl;
    __syncthreads();
    for (int i = t; i < cnt; i += 256) {
        uint_t e = bebuf[ebase + i];
        int dl = (int)(e >> 24);
        int pos = atomicAdd(&cur[dl], 1);
        csr[ebase + pos] = (int)(e & 0xFFFFFFu);
    }
    __syncthreads();
    if (t < DBINS) {
        int c = dh[t];
        if (c) atomicAdd(&dhist[t], c);
    }
}

// ---------- degree-balance sort (scan + perm) ----------

__global__ void k_dscan(const int* __restrict__ dhist, int* __restrict__ dcur) {  // 1 block, 64 thr
    __shared__ int l[DBINS];
    int t = threadIdx.x;
    int v = dhist[t];
    l[t] = v;
    __syncthreads();
    for (int off = 1; off < DBINS; off <<= 1) {
        int u = (t >= off) ? l[t - off] : 0;
        __syncthreads();
        l[t] += u;
        __syncthreads();
    }
    dcur[t] = l[t] - v;   // exclusive base
}

__global__ __launch_bounds__(256) void k_dperm(const int* __restrict__ rp, int N,
                                               int* __restrict__ dcur, int* __restrict__ perm) {
    __shared__ int h[DBINS];
    __shared__ int base[DBINS];
    int t = threadIdx.x;
    if (t < DBINS) h[t] = 0;
    __syncthreads();
    int i = blockIdx.x * 256 + t;
    int b = -1;
    if (i < N) {
        int d = rp[i + 1] - rp[i];
        b = min(d, DBINS - 1);
        atomicAdd(&h[b], 1);
    }
    __syncthreads();
    if (t < DBINS) {
        int v = h[t];
        base[t] = v ? atomicAdd(&dcur[t], v) : 0;
        h[t] = 0;
    }
    __syncthreads();
    if (i < N) {
        int off = atomicAdd(&h[b], 1);
        perm[base[b] + off] = i;
    }
}

// ---------- mean aggregation: 16 lanes per node, x4 edge unroll ----------
// System-throughput-bound gather (r1 88 vs r2 112 in-flight loads: identical
// perf) -> keep VGPR low (x4 unroll, ~67% occupancy) + 2-op/pair bf16 unpack.

__device__ __forceinline__ void acc8(float* a, uint4 p) {
    union { uint_t u; float f; } c;
    c.u = p.x << 16;         a[0] += c.f;
    c.u = p.x & 0xffff0000u; a[1] += c.f;
    c.u = p.y << 16;         a[2] += c.f;
    c.u = p.y & 0xffff0000u; a[3] += c.f;
    c.u = p.z << 16;         a[4] += c.f;
    c.u = p.z & 0xffff0000u; a[5] += c.f;
    c.u = p.w << 16;         a[6] += c.f;
    c.u = p.w & 0xffff0000u; a[7] += c.f;
}

__global__ __launch_bounds__(256) void k_agg(const ushort_t* __restrict__ X,
                                             const int* __restrict__ row_ptr,
                                             const int* __restrict__ csr,
                                             const int* __restrict__ perm,
                                             ushort_t* __restrict__ out, int n) {
    int g = (int)((blockIdx.x * (unsigned)blockDim.x + threadIdx.x) >> 4);
    if (g >= n) return;
    int node = perm[g];                      // degree-sorted work assignment
    int sl = threadIdx.x & 15;               // sub-lane: 8 bf16 = 16 B of the row
    int beg = row_ptr[node], end = row_ptr[node + 1];
    float a[8] = {0.f, 0.f, 0.f, 0.f, 0.f, 0.f, 0.f, 0.f};

    int e = beg;
    for (; e + 4 <= end; e += 4) {
        int s0 = csr[e + 0], s1 = csr[e + 1], s2 = csr[e + 2], s3 = csr[e + 3];
        uint4 p0 = *(const uint4*)(X + (size_t)s0 * DIM + sl * 8);
        uint4 p1 = *(const uint4*)(X + (size_t)s1 * DIM + sl * 8);
        uint4 p2 = *(const uint4*)(X + (size_t)s2 * DIM + sl * 8);
        uint4 p3 = *(const uint4*)(X + (size_t)s3 * DIM + sl * 8);
        acc8(a, p0); acc8(a, p1); acc8(a, p2); acc8(a, p3);
    }
    for (; e < end; e++) {
        int s = csr[e];
        uint4 p = *(const uint4*)(X + (size_t)s * DIM + sl * 8);
        acc8(a, p);
    }

    int cnt = end - beg;
    float sc = (cnt > 0) ? 1.f / (float)cnt : 0.f;
    uint4 o;
    o.x = (uint_t)f2bf(a[0] * sc) | ((uint_t)f2bf(a[1] * sc) << 16);
    o.y = (uint_t)f2bf(a[2] * sc) | ((uint_t)f2bf(a[3] * sc) << 16);
    o.z = (uint_t)f2bf(a[4] * sc) | ((uint_t)f2bf(a[5] * sc) << 16);
    o.w = (uint_t)f2bf(a[6] * sc) | ((uint_t)f2bf(a[7] * sc) << 16);
    *(uint4*)(out + (size_t)node * DIM + sl * 8) = o;
}

// ---------- persistent fused GEMM: stage weights once, grid-stride tiles ----------
// out = A1*W_l + A2*W_r + b. 128-row tiles, 4 waves/block (32 rows/wave).
// grid=512 (2 blocks/CU, LDS-limited): weights staged ONCE per block, then
// tiles processed with register-double-buffered A prefetch (next tile's A
// loads issued before current tile's MFMAs; in-order vmcnt leaves them in
// flight). Single barrier per block lifetime -> waves de-phase -> setprio(1)
// around the MFMA cluster pays (attn-like regime, m191).
// MFMA 16x16x32 bf16 layouts (m89-verified):
//   A frag: lane holds A[m=lane&15][k=quad*8+j]
//   B frag: lane holds B[k=quad*8+j][n=lane&15] = WT[n=lane&15][k=quad*8+j]
//   C/D   : col=lane&15, row=quad*4+reg

template <bool RELU, bool OUT_BF16>
struct GemmBody {
    const ushort_t* A1;
    const ushort_t* A2;
    const ushort_t* sW;
    void* Out;
    int M;
    int w, col, quad;
    float bv[8];

    __device__ __forceinline__ void loadA(bf16x8 (&a)[2][8], int tile) const {
#pragma unroll
        for (int tt = 0; tt < 2; tt++) {
            int arow = tile * 128 + w * 32 + tt * 16 + col;
            const ushort_t* a1p = A1 + (size_t)arow * DIM + quad * 8;
            const ushort_t* a2p = A2 + (size_t)arow * DIM + quad * 8;
#pragma unroll
            for (int ks = 0; ks < 4; ks++) a[tt][ks] = *(const bf16x8*)(a1p + ks * 32);
#pragma unroll
            for (int ks = 0; ks < 4; ks++) a[tt][4 + ks] = *(const bf16x8*)(a2p + ks * 32);
        }
    }

    __device__ __forceinline__ void compute(const bf16x8 (&a)[2][8], int tile) const {
        f32x4 acc[2][8];
#pragma unroll
        for (int tt = 0; tt < 2; tt++)
#pragma unroll
            for (int nt = 0; nt < 8; nt++) acc[tt][nt] = (f32x4){0.f, 0.f, 0.f, 0.f};

        const ushort_t* sWl = sW;
        const ushort_t* sWr = sW + 128 * 128;
        __builtin_amdgcn_s_setprio(1);
#pragma unroll
        for (int nt = 0; nt < 8; nt++) {
            int row = nt * 16 + col;
            const ushort_t* bl = sWl + (size_t)row * 128;
            const ushort_t* br = sWr + (size_t)row * 128;
#pragma unroll
            for (int ks = 0; ks < 4; ks++) {
                bf16x8 b = *(const bf16x8*)(bl + (((ks * 4 + quad) ^ col) * 8));
                acc[0][nt] = __builtin_amdgcn_mfma_f32_16x16x32_bf16(a[0][ks], b, acc[0][nt], 0, 0, 0);
                acc[1][nt] = __builtin_amdgcn_mfma_f32_16x16x32_bf16(a[1][ks], b, acc[1][nt], 0, 0, 0);
            }
#pragma unroll
            for (int ks = 0; ks < 4; ks++) {
                bf16x8 b = *(const bf16x8*)(br + (((ks * 4 + quad) ^ col) * 8));
                acc[0][nt] = __builtin_amdgcn_mfma_f32_16x16x32_bf16(a[0][4 + ks], b, acc[0][nt], 0, 0, 0);
                acc[1][nt] = __builtin_amdgcn_mfma_f32_16x16x32_bf16(a[1][4 + ks], b, acc[1][nt], 0, 0, 0);
            }
        }
        __builtin_amdgcn_s_setprio(0);

#pragma unroll
        for (int tt = 0; tt < 2; tt++)
#pragma unroll
            for (int nt = 0; nt < 8; nt++) {
                int c = nt * 16 + col;
#pragma unroll
                for (int r = 0; r < 4; r++) {
                    int m = tile * 128 + w * 32 + tt * 16 + quad * 4 + r;
                    if (m < M) {
                        float v = acc[tt][nt][r] + bv[nt];
                        if (RELU) v = v > 0.f ? v : 0.f;
                        if (OUT_BF16)
                            ((ushort_t*)Out)[(size_t)m * DIM + c] = f2bf(v);
                        else
                            ((float*)Out)[(size_t)m * DIM + c] = v;
                    }
                }
            }
    }
};

template <bool RELU, bool OUT_BF16>
__global__ __launch_bounds__(256, 2) void k_gemm(const ushort_t* __restrict__ A1,
                                                 const ushort_t* __restrict__ A2,
                                                 const ushort_t* __restrict__ WTl,
                                                 const ushort_t* __restrict__ WTr,
                                                 const float* __restrict__ bias,
                                                 void* __restrict__ Out, int ntiles, int M) {
    __shared__ ushort_t sW[2 * 128 * 128];   // 64 KB
    int t = threadIdx.x;

    GemmBody<RELU, OUT_BF16> gb;
    gb.A1 = A1; gb.A2 = A2; gb.sW = sW; gb.Out = Out; gb.M = M;
    gb.w = t >> 6;
    int lane = t & 63;
    gb.col = lane & 15;
    gb.quad = lane >> 4;
#pragma unroll
    for (int nt = 0; nt < 8; nt++) gb.bv[nt] = bias[nt * 16 + gb.col];

    // first tile's A loads issued before staging sync (latency overlap)
    int tile = blockIdx.x;
    bf16x8 aA[2][8], aB[2][8];
    gb.loadA(aA, tile);

    // stage both weight tables once: thread t copies one row, XOR-swizzled at
    // 16B-chunk granularity (chunk c of row n at c^(n&15): ds_read_b128
    // fragment reads <=2-way bank-aliased, free per m136)
    {
        int tab = t >> 7, row = t & 127;
        const ushort_t* g = (tab ? WTr : WTl) + (size_t)row * 128;
        ushort_t* d = sW + (size_t)t * 128;
        int sw = row & 15;
#pragma unroll
        for (int c = 0; c < 16; c++) {
            uint4 v = *(const uint4*)(g + c * 8);
            *(uint4*)(d + ((c ^ sw) * 8)) = v;
        }
    }
    __syncthreads();

    int step = gridDim.x;
    while (true) {
        int t2 = tile + step;
        if (t2 < ntiles) gb.loadA(aB, t2);      // prefetch into other buffer
        gb.compute(aA, tile);
        tile = t2;
        if (tile >= ntiles) break;

        int t3 = tile + step;
        if (t3 < ntiles) gb.loadA(aA, t3);
        gb.compute(aB, tile);
        tile = t3;
        if (tile >= ntiles) break;
    }
}

// ---------- host ----------

extern "C" void kernel_launch(void* const* d_in, const int* in_sizes, int n_in,
                              void* d_out, int out_size, void* d_ws, size_t ws_size,
                              hipStream_t stream) {
    const int N = in_sizes[0] / DIM;   // 100000
    const int E = in_sizes[1] / 2;     // 1600000
    const int NB = (N + BNODES - 1) >> BSHIFT;   // 391 buckets

    const float* x   = (const float*)d_in[0];
    const int*   ei  = (const int*)d_in[1];
    const int*   src = ei;
    const int*   dst = ei + E;
    const float* W1l = (const float*)d_in[2];
    const float* b1  = (const float*)d_in[3];
    const float* W1r = (const float*)d_in[4];
    const float* W2l = (const float*)d_in[5];
    const float* b2  = (const float*)d_in[6];
    const float* W2r = (const float*)d_in[7];
    float* out = (float*)d_out;

    char* ws = (char*)d_ws;
    size_t off = 0;
    auto alloc = [&](size_t bytes) -> char* {
        char* p = ws + off;
        off = (off + bytes + 255) & ~(size_t)255;
        return p;
    };

    int*      bucketCount  = (int*)alloc((size_t)NB * 4);
    int*      dhist        = (int*)alloc((size_t)DBINS * 4);   // adjacent to bucketCount: one memset
    int*      dcur         = (int*)alloc((size_t)DBINS * 4);   // fully written by k_dscan
    int*      bucketBase   = (int*)alloc((size_t)NB * 4);
    int*      bucketCursor = (int*)alloc((size_t)NB * 4);
    int*      row_ptr      = (int*)alloc((size_t)(N + 1) * 4);
    int*      csr          = (int*)alloc((size_t)E * 4);
    uint_t*   bebuf        = (uint_t*)alloc((size_t)E * 4);
    size_t    fpad         = (size_t)128 * DIM * 2;  // tile-padding for 128-row-tile A loads
    ushort_t* xb           = (ushort_t*)alloc((size_t)N * DIM * 2 + fpad);
    ushort_t* hb           = (ushort_t*)alloc((size_t)N * DIM * 2 + fpad);
    ushort_t* aggb         = (ushort_t*)alloc((size_t)N * DIM * 2 + fpad);
    ushort_t* wt1l         = (ushort_t*)alloc((size_t)DIM * DIM * 2);
    ushort_t* wt1r         = (ushort_t*)alloc((size_t)DIM * DIM * 2);
    ushort_t* wt2l         = (ushort_t*)alloc((size_t)DIM * DIM * 2);
    ushort_t* wt2r         = (ushort_t*)alloc((size_t)DIM * DIM * 2);
    int*      perm         = (int*)bebuf;   // bebuf is dead after k_bcsr; reuse as perm

    // zero bucket histogram + degree histogram in one shot (ws is poisoned each call)
    hipMemsetAsync(bucketCount, 0, (size_t)((char*)dhist - (char*)bucketCount) + DBINS * 4, stream);

    // x -> bf16 cast + weight transposes + bucket histogram, single launch
    {
        int n4 = N * DIM / 4;
        int total = n4 + 4 * DIM * DIM;
        int prepBlocks = (total + 255) / 256;
        k_prep_bhist<<<dim3(prepBlocks + 256), dim3(256), 0, stream>>>(
            x, xb, n4, W1l, W1r, W2l, W2r, wt1l, wt1r, wt2l, wt2r,
            dst, E, NB, bucketCount, prepBlocks);
    }
    // CSR build: bucket counting sort (degree histogram folded into k_bcsr)
    k_bscan<<<dim3(1), dim3(512), 0, stream>>>(bucketCount, NB, E, bucketBase, bucketCursor, row_ptr, N);
    k_bucketize<<<dim3(256), dim3(256), 0, stream>>>(src, dst, E, NB, bucketCursor, bebuf);
    k_bcsr<<<dim3(NB), dim3(256), 0, stream>>>(bebuf, bucketBase, bucketCount, N, row_ptr, csr, dhist);

    // degree-balance permutation (bebuf dead from here; perm aliases it)
    const int nblk = (N + 255) / 256;
    k_dscan<<<dim3(1), dim3(DBINS), 0, stream>>>(dhist, dcur);
    k_dperm<<<dim3(nblk), dim3(256), 0, stream>>>(row_ptr, N, dcur, perm);

    const int ntiles = (N + 127) / 128;                         // 782
    dim3 gemm_grid((unsigned)min(ntiles, 512)), gemm_blk(256);
    dim3 agg_grid((N + 15) / 16), agg_blk(256);                 // 16 nodes/block (16 lanes/node)

    // layer 1
    k_agg<<<agg_grid, agg_blk, 0, stream>>>(xb, row_ptr, csr, perm, aggb, N);
    k_gemm<true, true><<<gemm_grid, gemm_blk, 0, stream>>>(aggb, xb, wt1l, wt1r, b1, hb, ntiles, N);
    // layer 2
    k_agg<<<agg_grid, agg_blk, 0, stream>>>(hb, row_ptr, csr, perm, aggb, N);
    k_gemm<false, false><<<gemm_grid, gemm_blk, 0, stream>>>(aggb, hb, wt2l, wt2r, b2, out, ntiles, N);

    (void)n_in; (void)out_size; (void)ws_size;
}

// Round 4
// 319.689 us; speedup vs baseline: 1.1731x; 1.1093x over previous
//
#include <hip/hip_runtime.h>

typedef unsigned short ushort_t;
typedef unsigned int uint_t;

typedef short bf16x8 __attribute__((ext_vector_type(8)));
typedef float f32x4 __attribute__((ext_vector_type(4)));

#define DIM 128
#define BSHIFT 8
#define BNODES 256           // nodes per bucket (1<<BSHIFT)
#define DBINS 64             // degree bins for balance-sort (Poisson(16): max deg ~45)

__device__ __forceinline__ ushort_t f2bf(float f) {
    uint_t x;
    __builtin_memcpy(&x, &f, 4);
    uint_t r = (x + 0x7fffu + ((x >> 16) & 1u)) >> 16;
    return (ushort_t)r;
}

// ---------- prep: x->bf16 cast + fragment-major weight buffers + bhist ----------
// fragbuf layout (per layer, 64 KB): frag f = nt*8+ks2 covers output cols
// [nt*16,nt*16+16) x K-chunk [ks2*32,ks2*32+32) of the concatenated K=256 GEMM
// (k2<128 -> W_l[k2][n], k2>=128 -> W_r[k2-128][n]). Within a frag, lane
// l=(quad,col) holds B[k=quad*8+j][n=col] at fragbuf[f*512 + l*8 + j] — so a
// wave's B-frag load is ONE fully-coalesced 1KB global_load_dwordx4 (L1-hot).

__global__ __launch_bounds__(256) void k_prep_bhist(
        const float* __restrict__ x, ushort_t* __restrict__ xb, int n4,
        const float* __restrict__ W1l, const float* __restrict__ W1r,
        const float* __restrict__ W2l, const float* __restrict__ W2r,
        ushort_t* __restrict__ fragbuf,
        const int* __restrict__ dst, int E, int NB, int* __restrict__ bucketCount,
        int prepBlocks) {
    if ((int)blockIdx.x >= prepBlocks) {
        __shared__ int hist[512];
        int blk = blockIdx.x - prepBlocks;   // 0..255
        int t = threadIdx.x;
        for (int b = t; b < NB; b += 256) hist[b] = 0;
        __syncthreads();
        int per = (E + 255) / 256;
        int beg = blk * per, end = min(beg + per, E);
        for (int i = beg + t; i < end; i += 256)
            atomicAdd(&hist[dst[i] >> BSHIFT], 1);
        __syncthreads();
        for (int b = t; b < NB; b += 256) {
            int v = hist[b];
            if (v) atomicAdd(&bucketCount[b], v);
        }
        return;
    }
    int i = blockIdx.x * 256 + threadIdx.x;
    if (i < n4) {
        float4 f = ((const float4*)x)[i];
        ushort4 u;
        u.x = f2bf(f.x); u.y = f2bf(f.y); u.z = f2bf(f.z); u.w = f2bf(f.w);
        ((ushort4*)xb)[i] = u;
    } else {
        int j = i - n4;                       // 0 .. 8191
        if (j < 2 * 64 * 64) {
            int layer = j >> 12;
            int rr = j & 4095;
            int f = rr >> 6, l = rr & 63;
            int nt = f >> 3, ks2 = f & 7;
            int col = l & 15, quad = l >> 4;
            int n = nt * 16 + col;
            int kb = ks2 * 32 + quad * 8;
            const float* Wl = layer ? W2l : W1l;
            const float* Wr = layer ? W2r : W1r;
            ushort_t* d = fragbuf + layer * 32768 + f * 512 + l * 8;
#pragma unroll
            for (int jj = 0; jj < 8; jj++) {
                int k2 = kb + jj;
                float v = (k2 < 128) ? Wl[k2 * DIM + n] : Wr[(k2 - 128) * DIM + n];
                d[jj] = f2bf(v);
            }
        }
    }
}

// ---------- CSR build via two-level bucket counting sort ----------
// k_bucketize does its own local scan of bucketCount (kills the k_bscan
// launch); reservations go through zero-initialized global cursors zcur.
// Block 0 publishes bucketBase for k_bcsr and row_ptr[N]=E.

__global__ __launch_bounds__(256) void k_bucketize(const int* __restrict__ src,
                                                   const int* __restrict__ dst, int E, int NB,
                                                   const int* __restrict__ bucketCount,
                                                   int* __restrict__ bucketBase_out,
                                                   int* __restrict__ row_ptr, int N,
                                                   int* __restrict__ zcur,
                                                   uint_t* __restrict__ bebuf) {
    __shared__ int bbase[512];
    __shared__ int hist[512];
    __shared__ int rbase[512];
    int t = threadIdx.x;
    int i0 = t, i1 = t + 256;
    int v0 = (i0 < NB) ? bucketCount[i0] : 0;
    int v1 = (i1 < NB) ? bucketCount[i1] : 0;
    bbase[i0] = v0; bbase[i1] = v1;
    __syncthreads();
    for (int off = 1; off < 512; off <<= 1) {
        int u0 = (i0 >= off) ? bbase[i0 - off] : 0;
        int u1 = (i1 >= off) ? bbase[i1 - off] : 0;
        __syncthreads();
        bbase[i0] += u0; bbase[i1] += u1;
        __syncthreads();
    }
    bbase[i0] -= v0;    // exclusive (own-slot update, later reads after barriers)
    bbase[i1] -= v1;
    if (blockIdx.x == 0) {
        if (i0 < NB) bucketBase_out[i0] = bbase[i0];
        if (i1 < NB) bucketBase_out[i1] = bbase[i1];
        if (t == 0) row_ptr[N] = E;
    }
    hist[i0] = 0; hist[i1] = 0;
    __syncthreads();
    int per = (E + gridDim.x - 1) / gridDim.x;
    int beg = blockIdx.x * per, end = min(beg + per, E);
    for (int i = beg + t; i < end; i += 256)
        atomicAdd(&hist[dst[i] >> BSHIFT], 1);
    __syncthreads();
    {
        int v = hist[i0];
        rbase[i0] = v ? (bbase[i0] + atomicAdd(&zcur[i0], v)) : 0;
        hist[i0] = 0;
        v = hist[i1];
        rbase[i1] = v ? (bbase[i1] + atomicAdd(&zcur[i1], v)) : 0;
        hist[i1] = 0;
    }
    __syncthreads();
    for (int i = beg + t; i < end; i += 256) {
        int d = dst[i], s = src[i];
        int b = d >> BSHIFT;
        int off = atomicAdd(&hist[b], 1);
        bebuf[rbase[b] + off] = ((uint_t)(d & (BNODES - 1)) << 24) | (uint_t)s;
    }
}

// k_bcsr also folds the degree histogram for the balance-sort: after the count
// phase, hist[t] IS deg(node nodeBase+t).
__global__ __launch_bounds__(256) void k_bcsr(const uint_t* __restrict__ bebuf,
                                              const int* __restrict__ bucketBase,
                                              const int* __restrict__ bucketCount, int N,
                                              int* __restrict__ row_ptr, int* __restrict__ csr,
                                              int* __restrict__ dhist) {
    __shared__ int hist[BNODES];
    __shared__ int cur[BNODES];
    __shared__ int dh[DBINS];
    int t = threadIdx.x;
    int b = blockIdx.x;
    int ebase = bucketBase[b], cnt = bucketCount[b];
    int nodeBase = b << BSHIFT;
    hist[t] = 0;
    if (t < DBINS) dh[t] = 0;
    __syncthreads();
    for (int i = t; i < cnt; i += 256)
        atomicAdd(&hist[bebuf[ebase + i] >> 24], 1);
    __syncthreads();
    int v = hist[t];
    int node = nodeBase + t;
    if (node < N) atomicAdd(&dh[min(v, DBINS - 1)], 1);
    for (int off = 1; off < 256; off <<= 1) {
        int u = (t >= off) ? hist[t - off] : 0;
        __syncthreads();
        hist[t] += u;
        __syncthreads();
    }
    int excl = hist[t] - v;
    if (node < N) row_ptr[node] = ebase + excl;
    cur[t] = excl;
    __syncthreads();
    for (int i = t; i < cnt; i += 256) {
        uint_t e = bebuf[ebase + i];
        int dl = (int)(e >> 24);
        int pos = atomicAdd(&cur[dl], 1);
        csr[ebase + pos] = (int)(e & 0xFFFFFFu);
    }
    __syncthreads();
    if (t < DBINS) {
        int c = dh[t];
        if (c) atomicAdd(&dhist[t], c);
    }
}

// ---------- degree-balance permutation (local scan of dhist; kills k_dscan) ----------

__global__ __launch_bounds__(256) void k_dperm(const int* __restrict__ rp, int N,
                                               const int* __restrict__ dhist,
                                               int* __restrict__ zdcur, int* __restrict__ perm) {
    __shared__ int eb[DBINS];
    __shared__ int h[DBINS];
    __shared__ int rb[DBINS];
    int t = threadIdx.x;
    int v = (t < DBINS) ? dhist[t] : 0;
    if (t < DBINS) { eb[t] = v; h[t] = 0; }
    __syncthreads();
    for (int off = 1; off < DBINS; off <<= 1) {
        int u = (t < DBINS && t >= off) ? eb[t - off] : 0;
        __syncthreads();
        if (t < DBINS) eb[t] += u;
        __syncthreads();
    }
    if (t < DBINS) eb[t] -= v;   // exclusive base (own-slot)
    int i = blockIdx.x * 256 + t;
    int b = -1;
    if (i < N) {
        int d = rp[i + 1] - rp[i];
        b = min(d, DBINS - 1);
        atomicAdd(&h[b], 1);
    }
    __syncthreads();
    if (t < DBINS) {
        int hv = h[t];
        rb[t] = hv ? (eb[t] + atomicAdd(&zdcur[t], hv)) : 0;
        h[t] = 0;
    }
    __syncthreads();
    if (i < N) {
        int off = atomicAdd(&h[b], 1);
        perm[rb[b] + off] = i;
    }
}

// ---------- fused aggregate + SAGE GEMM ----------
// Block = 4 waves = 16 perm-consecutive (equal-degree) nodes.
// Phase 1 (identical shape to the old k_agg): 16 lanes/node gather+mean,
//   result packed bf16 into an 8KB LDS tile [16 rows][256 dims] = [agg | self]
//   (concatenated K=256 GEMM vs [W_l ; W_r]). 16B chunks XOR-swizzled by
//   (row&7) -> gather writes <=2-way, frag reads perfectly bank-balanced.
// Phase 2: wave w computes output cols [w*32, w*32+32): A-frags from LDS,
//   B-frags coalesced from fragbuf (L1-hot), 16 MFMAs, bias(+ReLU), store.
// Numerics identical to the previous agg->bf16->gemm pipeline.

__device__ __forceinline__ void acc8(float* a, uint4 p) {
    union { uint_t u; float f; } c;
    c.u = p.x << 16;         a[0] += c.f;
    c.u = p.x & 0xffff0000u; a[1] += c.f;
    c.u = p.y << 16;         a[2] += c.f;
    c.u = p.y & 0xffff0000u; a[3] += c.f;
    c.u = p.z << 16;         a[4] += c.f;
    c.u = p.z & 0xffff0000u; a[5] += c.f;
    c.u = p.w << 16;         a[6] += c.f;
    c.u = p.w & 0xffff0000u; a[7] += c.f;
}

template <bool RELU, bool OUT_BF16>
__global__ __launch_bounds__(256) void k_fused(const ushort_t* __restrict__ X,
                                               const int* __restrict__ row_ptr,
                                               const int* __restrict__ csr,
                                               const int* __restrict__ perm,
                                               const ushort_t* __restrict__ fragbuf,
                                               const float* __restrict__ bias,
                                               void* __restrict__ Out, int N) {
    __shared__ __align__(16) ushort_t tile[16 * 256];   // 8 KB
    __shared__ int nd[16];
    int t = threadIdx.x;
    int gl = t >> 4;                 // node slot 0..15
    int sl = t & 15;                 // 16B slice of the row
    int gidx = blockIdx.x * 16 + gl;
    bool act = (gidx < N);
    int node = 0, beg = 0, end = 0;
    if (act) {
        node = perm[gidx];
        beg = row_ptr[node];
        end = row_ptr[node + 1];
    }
    if (sl == 0) nd[gl] = node;

    // ---- gather (x4 unroll, same as proven k_agg) ----
    float a[8] = {0.f, 0.f, 0.f, 0.f, 0.f, 0.f, 0.f, 0.f};
    int e = beg;
    for (; e + 4 <= end; e += 4) {
        int s0 = csr[e + 0], s1 = csr[e + 1], s2 = csr[e + 2], s3 = csr[e + 3];
        uint4 p0 = *(const uint4*)(X + (size_t)s0 * DIM + sl * 8);
        uint4 p1 = *(const uint4*)(X + (size_t)s1 * DIM + sl * 8);
        uint4 p2 = *(const uint4*)(X + (size_t)s2 * DIM + sl * 8);
        uint4 p3 = *(const uint4*)(X + (size_t)s3 * DIM + sl * 8);
        acc8(a, p0); acc8(a, p1); acc8(a, p2); acc8(a, p3);
    }
    for (; e < end; e++) {
        int s = csr[e];
        uint4 p = *(const uint4*)(X + (size_t)s * DIM + sl * 8);
        acc8(a, p);
    }
    int cnt = end - beg;
    float scl = (cnt > 0) ? 1.f / (float)cnt : 0.f;

    int swz = gl & 7;
    uint4 o;
    o.x = (uint_t)f2bf(a[0] * scl) | ((uint_t)f2bf(a[1] * scl) << 16);
    o.y = (uint_t)f2bf(a[2] * scl) | ((uint_t)f2bf(a[3] * scl) << 16);
    o.z = (uint_t)f2bf(a[4] * scl) | ((uint_t)f2bf(a[5] * scl) << 16);
    o.w = (uint_t)f2bf(a[6] * scl) | ((uint_t)f2bf(a[7] * scl) << 16);
    *(uint4*)(tile + gl * 256 + ((sl ^ swz) * 8)) = o;           // agg dims
    uint4 p;
    if (act) p = *(const uint4*)(X + (size_t)node * DIM + sl * 8);
    else     p = (uint4){0u, 0u, 0u, 0u};
    *(uint4*)(tile + gl * 256 + (((16 + sl) ^ swz) * 8)) = p;    // self dims
    __syncthreads();

    // ---- MFMA phase ----
    int lane = t & 63, w = t >> 6;
    int m = lane & 15, quad = lane >> 4;
    bf16x8 af[8];
#pragma unroll
    for (int ks2 = 0; ks2 < 8; ks2++) {
        int c = (ks2 * 4 + quad) ^ (m & 7);
        af[ks2] = *(const bf16x8*)(tile + m * 256 + c * 8);
    }
    f32x4 acc0 = (f32x4){0.f, 0.f, 0.f, 0.f};
    f32x4 acc1 = (f32x4){0.f, 0.f, 0.f, 0.f};
    const ushort_t* fb0 = fragbuf + (size_t)((w * 2 + 0) * 8) * 512 + lane * 8;
    const ushort_t* fb1 = fragbuf + (size_t)((w * 2 + 1) * 8) * 512 + lane * 8;
#pragma unroll
    for (int ks2 = 0; ks2 < 8; ks2++) {
        bf16x8 b0 = *(const bf16x8*)(fb0 + ks2 * 512);
        acc0 = __builtin_amdgcn_mfma_f32_16x16x32_bf16(af[ks2], b0, acc0, 0, 0, 0);
    }
#pragma unroll
    for (int ks2 = 0; ks2 < 8; ks2++) {
        bf16x8 b1 = *(const bf16x8*)(fb1 + ks2 * 512);
        acc1 = __builtin_amdgcn_mfma_f32_16x16x32_bf16(af[ks2], b1, acc1, 0, 0, 0);
    }
    int c0 = (w * 2 + 0) * 16 + m;
    int c1 = (w * 2 + 1) * 16 + m;
    float bv0 = bias[c0], bv1 = bias[c1];
#pragma unroll
    for (int r = 0; r < 4; r++) {
        int mrow = quad * 4 + r;
        int gI = blockIdx.x * 16 + mrow;
        if (gI < N) {
            int nodeW = nd[mrow];
            float v0 = acc0[r] + bv0;
            float v1 = acc1[r] + bv1;
            if (RELU) { v0 = fmaxf(v0, 0.f); v1 = fmaxf(v1, 0.f); }
            if (OUT_BF16) {
                ((ushort_t*)Out)[(size_t)nodeW * DIM + c0] = f2bf(v0);
                ((ushort_t*)Out)[(size_t)nodeW * DIM + c1] = f2bf(v1);
            } else {
                ((float*)Out)[(size_t)nodeW * DIM + c0] = v0;
                ((float*)Out)[(size_t)nodeW * DIM + c1] = v1;
            }
        }
    }
}

// ---------- host ----------

extern "C" void kernel_launch(void* const* d_in, const int* in_sizes, int n_in,
                              void* d_out, int out_size, void* d_ws, size_t ws_size,
                              hipStream_t stream) {
    const int N = in_sizes[0] / DIM;   // 100000
    const int E = in_sizes[1] / 2;     // 1600000
    const int NB = (N + BNODES - 1) >> BSHIFT;   // 391 buckets

    const float* x   = (const float*)d_in[0];
    const int*   ei  = (const int*)d_in[1];
    const int*   src = ei;
    const int*   dst = ei + E;
    const float* W1l = (const float*)d_in[2];
    const float* b1  = (const float*)d_in[3];
    const float* W1r = (const float*)d_in[4];
    const float* W2l = (const float*)d_in[5];
    const float* b2  = (const float*)d_in[6];
    const float* W2r = (const float*)d_in[7];
    float* out = (float*)d_out;

    char* ws = (char*)d_ws;
    size_t off = 0;
    auto alloc = [&](size_t bytes) -> char* {
        char* p = ws + off;
        off = (off + bytes + 255) & ~(size_t)255;
        return p;
    };

    // zero-init span: bucketCount, dhist, zcur, zdcur (contiguous allocs)
    int*      bucketCount  = (int*)alloc((size_t)NB * 4);
    int*      dhist        = (int*)alloc((size_t)DBINS * 4);
    int*      zcur         = (int*)alloc((size_t)NB * 4);
    int*      zdcur        = (int*)alloc((size_t)DBINS * 4);
    size_t    zspan        = (size_t)((char*)zdcur + DBINS * 4 - (char*)bucketCount);
    int*      bucketBase   = (int*)alloc((size_t)NB * 4);
    int*      row_ptr      = (int*)alloc((size_t)(N + 1) * 4);
    int*      csr          = (int*)alloc((size_t)E * 4);
    uint_t*   bebuf        = (uint_t*)alloc((size_t)E * 4);
    ushort_t* xb           = (ushort_t*)alloc((size_t)N * DIM * 2);
    ushort_t* hb           = (ushort_t*)alloc((size_t)N * DIM * 2);
    ushort_t* fragbuf      = (ushort_t*)alloc((size_t)2 * 32768 * 2);   // 2 layers x 64 KB
    int*      perm         = (int*)bebuf;   // bebuf dead after k_bcsr; reuse as perm

    hipMemsetAsync(bucketCount, 0, zspan, stream);

    // x->bf16 + fragment-major weights + bucket histogram, single launch
    {
        int n4 = N * DIM / 4;
        int total = n4 + 2 * 64 * 64;
        int prepBlocks = (total + 255) / 256;
        k_prep_bhist<<<dim3(prepBlocks + 256), dim3(256), 0, stream>>>(
            x, xb, n4, W1l, W1r, W2l, W2r, fragbuf,
            dst, E, NB, bucketCount, prepBlocks);
    }
    // CSR build (bucketize self-scans; bcsr folds degree histogram)
    k_bucketize<<<dim3(256), dim3(256), 0, stream>>>(src, dst, E, NB, bucketCount,
                                                     bucketBase, row_ptr, N, zcur, bebuf);
    k_bcsr<<<dim3(NB), dim3(256), 0, stream>>>(bebuf, bucketBase, bucketCount, N,
                                               row_ptr, csr, dhist);
    // degree-balance permutation (self-scans dhist; perm aliases bebuf)
    const int nblk = (N + 255) / 256;
    k_dperm<<<dim3(nblk), dim3(256), 0, stream>>>(row_ptr, N, dhist, zdcur, perm);

    const int ntiles = (N + 15) / 16;    // 6250 blocks, same grid shape as old k_agg
    k_fused<true, true><<<dim3(ntiles), dim3(256), 0, stream>>>(
        xb, row_ptr, csr, perm, fragbuf, b1, hb, N);
    k_fused<false, false><<<dim3(ntiles), dim3(256), 0, stream>>>(
        hb, row_ptr, csr, perm, fragbuf + 32768, b2, out, N);

    (void)n_in; (void)out_size; (void)ws_size;
}